// Round 8
// baseline (199.471 us; speedup 1.0000x reference)
//
#include <hip/hip_runtime.h>

namespace {

constexpr int BATCH = 16;
constexpr int HH = 512;
constexpr int WW = 512;
constexpr int PLANE = HH * WW;
constexpr int NPAIR = BATCH * (HH / 8) * (WW / 16);  // 32768 block-pairs
constexpr int NWG = 16384;                           // ITERS=2, fine tails

// ---- numpy-faithful cosine table (decision-path numerics) ----
constexpr double PI64 = 3.141592653589793;
constexpr double PI_LO = 1.2246467991473532e-16;
constexpr double PI_HI = (double)((long long)(PI64 * 17592186044416.0)) / 17592186044416.0;
constexpr double PI_MID = PI64 - PI_HI;

constexpr double CD9[9] = {
    1.0,
    0.9807852804032304491,
    0.9238795325112867561,
    0.8314696123025452371,
    0.7071067811865475244,
    0.5555702330196022248,
    0.3826834323650897717,
    0.1950903220161282678,
    0.0};
constexpr double cos_tab(int m) {
    m %= 32;
    double s = 1.0;
    if (m > 16) m = 32 - m;
    if (m > 8) { s = -1.0; m = 16 - m; }
    return s * CD9[m];
}
constexpr double sin_tab(int m) { return cos_tab(m + 24); }

constexpr double cx64(int K) {
    float Kf = (float)K;
    float p32 = (float)PI64;
    float t32 = Kf * p32;
    double F = (double)t32;
    double E = ((F - (double)K * PI_HI) - (double)K * PI_MID) - (double)K * PI_LO;
    double r = E / 16.0;
    double C = cos_tab(K), S = sin_tab(K);
    double cr = 1.0 - 0.5 * r * r;
    double sr = r - (r * r * r) / 6.0;
    return C * cr - S * sr;
}
constexpr float cx32(int x, int u) { return (float)cx64((2 * x + 1) * u); }

struct C32A { float c[64]; };
constexpr C32A make_c32f() {
    C32A a{};
    for (int x = 0; x < 8; ++x)
        for (int u = 0; u < 8; ++u)
            a.c[x * 8 + u] = cx32(x, u);
    return a;
}
constexpr C32A C32F = make_c32f();

constexpr float YQ[64] = {
    16, 11, 10, 16, 24, 40, 51, 61,
    12, 12, 14, 19, 26, 58, 60, 55,
    14, 13, 16, 24, 40, 57, 69, 56,
    14, 17, 22, 29, 51, 87, 80, 62,
    18, 22, 37, 56, 68, 109, 103, 77,
    24, 35, 55, 64, 81, 104, 113, 92,
    49, 64, 78, 87, 103, 121, 120, 101,
    72, 92, 95, 98, 112, 100, 103, 99};

constexpr float CQ[64] = {
    17, 18, 24, 47, 99, 99, 99, 99,
    18, 21, 26, 66, 99, 99, 99, 99,
    24, 26, 56, 99, 99, 99, 99, 99,
    47, 66, 99, 99, 99, 99, 99, 99,
    99, 99, 99, 99, 99, 99, 99, 99,
    99, 99, 99, 99, 99, 99, 99, 99,
    99, 99, 99, 99, 99, 99, 99, 99,
    99, 99, 99, 99, 99, 99, 99, 99};

constexpr float AL32 = (float)0.7071067811865475244;

} // namespace

// fp64 color transform — bit-identical (decision path).
__device__ __forceinline__ void color_f64(float Rf, float Gf, float Bf,
                                          double& yv, double& cbv, double& crv) {
    const double rv = ((double)Rf + 1.0) * 127.5;
    const double gv = ((double)Gf + 1.0) * 127.5;
    const double bv = ((double)Bf + 1.0) * 127.5;
    yv = ((double)0.299f * rv + (double)0.587f * gv) + (double)0.114f * bv;
    yv = yv - 128.0;
    cbv = ((double)-0.168736f * rv + (double)-0.331264f * gv) + (double)0.5f * bv;
    cbv = (cbv + 128.0) - 128.0;
    crv = ((double)0.5f * rv + (double)-0.418688f * gv) + (double)-0.081312f * bv;
    crv = (crv + 128.0) - 128.0;
}

__device__ __forceinline__ float clamp255(float x) {
    return fminf(fmaxf(x, 0.0f), 255.0f) * (1.0f / 255.0f);
}

// One wave = one PAIR of adjacent 8x8 blocks per iteration.
// Separable f64 DCT (verified R7, absmax-identical). This round:
//  - stage-B V gather and idct1 F gather via __shfl within the lane's own
//    8-lane group (V[px][y] / F[px][v] live at lane px*8+y) — removes the
//    sV and sF LDS buffers and two full lgkmcnt drains. Same FMA orders.
//  - sGt aliases dead sYd: LDS 8704 -> 3328 B; occupancy 4 -> 6 waves/SIMD.
//  - next-pair pixel prefetch (double-buffered regs) hides HBM latency.
__global__ __launch_bounds__(64, 6) void jpeg_kernel(const float* __restrict__ in,
                                                     float* __restrict__ out) {
    __shared__ __align__(16) char  sMem[3072];  // sYd, later aliased by sGt
    __shared__ __align__(16) float sC[64];      // fp32 cosines for IDCT

    double (*sYd)[3][64] = reinterpret_cast<double(*)[3][64]>(sMem);   // [blk][ch][x*8+y]
    float  (*sGt)[3][96] = reinterpret_cast<float(*)[3][96]>(sMem);    // [blk][ch][y*12+u]

    const int lane = threadIdx.x;     // 0..63
    const int px = lane >> 3;         // row within block / u-index
    const int py = lane & 7;          // col index        / v-index
    const int gbase = lane & 56;      // this lane's 8-lane group base (px*8)

    sC[lane] = C32F.c[lane];

    // per-lane f64 DCT factors (32 VGPRs, persistent):
    double cuD[8], cvD[8];
    #pragma unroll
    for (int k = 0; k < 8; ++k) {
        cuD[k] = (double)C32F.c[k * 8 + px];
        cvD[k] = (double)C32F.c[k * 8 + py];
    }

    // quant constants; f64 values re-derived per use exactly as the old QD table.
    const float yqf  = YQ[lane];
    const float cqf  = CQ[lane];
    const float aa32 = (px == 0 ? AL32 : 1.0f) * (py == 0 ? AL32 : 1.0f);
    const double aaD = (double)aa32;
    const double mQ  = (double)(aa32 * 0.25f);

    const int blkL = py >> 2;         // which block this lane's pixel-pair is in
    const int col0 = (py & 3) * 2;    // first of two adjacent columns in that block

    // ---- prologue: load first pair's pixels ----
    int P = blockIdx.x;
    size_t rowbase;
    float2 Rc, Gc, Bc;
    {
        const int b = P >> 11, p2 = P & 2047;
        rowbase = (size_t)b * 3 * PLANE + (size_t)((p2 >> 5) * 8 + px) * WW
                + (size_t)((p2 & 31) * 16);
        Rc = *(const float2*)(in + rowbase + 2 * py);
        Gc = *(const float2*)(in + rowbase + PLANE + 2 * py);
        Bc = *(const float2*)(in + rowbase + 2 * (size_t)PLANE + 2 * py);
    }

    #pragma unroll 1
    for (; P < NPAIR; P += NWG) {
        // ---- prefetch next pair (clamped; discarded on last iteration) ----
        const int Pn = (P + NWG < NPAIR) ? (P + NWG) : P;
        size_t rbn;
        {
            const int b = Pn >> 11, p2 = Pn & 2047;
            rbn = (size_t)b * 3 * PLANE + (size_t)((p2 >> 5) * 8 + px) * WW
                + (size_t)((p2 & 31) * 16);
        }
        const float2 Rn = *(const float2*)(in + rbn + 2 * py);
        const float2 Gn = *(const float2*)(in + rbn + PLANE + 2 * py);
        const float2 Bn = *(const float2*)(in + rbn + 2 * (size_t)PLANE + 2 * py);

        __syncthreads();   // Ba: prior iter's sGt reads done before sYd overwrite

        {
            double y0, cb0, cr0, y1, cb1, cr1;
            color_f64(Rc.x, Gc.x, Bc.x, y0, cb0, cr0);
            color_f64(Rc.y, Gc.y, Bc.y, y1, cb1, cr1);
            const int si = px * 8 + col0;
            *(double2*)&sYd[blkL][0][si] = make_double2(y0, y1);
            *(double2*)&sYd[blkL][1][si] = make_double2(cb0, cb1);
            *(double2*)&sYd[blkL][2][si] = make_double2(cr0, cr1);
        }
        __syncthreads();   // Bb: sYd complete

        // ---- DCT stage A: V[u=px][y=py] = sum_x cuD[x] * Y[x][py] (regs) ----
        double vA[3], vB[3];
        #pragma unroll
        for (int ch = 0; ch < 3; ++ch) {
            const double* __restrict__ Y0 = &sYd[0][ch][0];
            const double* __restrict__ Y1 = &sYd[1][ch][0];
            double a = 0.0, bb = 0.0;
            #pragma unroll
            for (int x = 0; x < 8; ++x) {
                a  = __builtin_fma(cuD[x], Y0[x * 8 + py], a);
                bb = __builtin_fma(cuD[x], Y1[x * 8 + py], bb);
            }
            vA[ch] = a; vB[ch] = bb;
        }

        // ---- DCT stage B via group shuffles + diff-round quant ----
        // V[px][y] lives at lane gbase+y; FMA order identical to R7 (y asc).
        float Fv0[3], Fv1[3];
        #pragma unroll
        for (int ch = 0; ch < 3; ++ch) {
            double sA = 0.0, sB = 0.0;
            #pragma unroll
            for (int y = 0; y < 8; ++y) {
                sA = __builtin_fma(cvD[y], __shfl(vA[ch], gbase + y, 64), sA);
                sB = __builtin_fma(cvD[y], __shfl(vB[ch], gbase + y, 64), sB);
            }
            const double qtd = (ch == 0) ? (double)yqf : (double)cqf;
            const double dq  = qtd * aaD;
            {
                const double f = (mQ * sA) / qtd;   // true f64 divide
                const double rr = __builtin_rint(f);
                const double d = f - rr;
                Fv0[ch] = (float)((rr + (d * d) * d) * dq);
            }
            {
                const double f = (mQ * sB) / qtd;
                const double rr = __builtin_rint(f);
                const double d = f - rr;
                Fv1[ch] = (float)((rr + (d * d) * d) * dq);
            }
        }

        __syncthreads();   // Bc: sYd reads done — sGt may overwrite (alias fence)

        // ---- idct1: G[u=px][y=py] = sum_v c[py][v]*F[px][v]; F via shuffles ----
        {
            const float4 cy0 = *(const float4*)&sC[py * 8];
            const float4 cy1 = *(const float4*)&sC[py * 8 + 4];
            #pragma unroll
            for (int ch = 0; ch < 3; ++ch) {
                float g0 = 0.0f, g1 = 0.0f;
                float f00 = __shfl(Fv0[ch], gbase + 0, 64);
                float f10 = __shfl(Fv1[ch], gbase + 0, 64);
                float f01 = __shfl(Fv0[ch], gbase + 1, 64);
                float f11 = __shfl(Fv1[ch], gbase + 1, 64);
                float f02 = __shfl(Fv0[ch], gbase + 2, 64);
                float f12 = __shfl(Fv1[ch], gbase + 2, 64);
                float f03 = __shfl(Fv0[ch], gbase + 3, 64);
                float f13 = __shfl(Fv1[ch], gbase + 3, 64);
                g0 += cy0.x * f00; g1 += cy0.x * f10;
                g0 += cy0.y * f01; g1 += cy0.y * f11;
                g0 += cy0.z * f02; g1 += cy0.z * f12;
                g0 += cy0.w * f03; g1 += cy0.w * f13;
                float f04 = __shfl(Fv0[ch], gbase + 4, 64);
                float f14 = __shfl(Fv1[ch], gbase + 4, 64);
                float f05 = __shfl(Fv0[ch], gbase + 5, 64);
                float f15 = __shfl(Fv1[ch], gbase + 5, 64);
                float f06 = __shfl(Fv0[ch], gbase + 6, 64);
                float f16 = __shfl(Fv1[ch], gbase + 6, 64);
                float f07 = __shfl(Fv0[ch], gbase + 7, 64);
                float f17 = __shfl(Fv1[ch], gbase + 7, 64);
                g0 += cy1.x * f04; g1 += cy1.x * f14;
                g0 += cy1.y * f05; g1 += cy1.y * f15;
                g0 += cy1.z * f06; g1 += cy1.z * f16;
                g0 += cy1.w * f07; g1 += cy1.w * f17;
                sGt[0][ch][py * 12 + px] = g0;   // (yy=py, uu=px)
                sGt[1][ch][py * 12 + px] = g1;
            }
        }
        __syncthreads();   // Bd: sGt complete

        // ---- idct2 + color-back: two ADJACENT pixels of blkL ----
        float r0[3], r1[3];
        {
            const float4 cx0 = *(const float4*)&sC[px * 8];
            const float4 cx1 = *(const float4*)&sC[px * 8 + 4];
            #pragma unroll
            for (int ch = 0; ch < 3; ++ch) {
                const float4 ga0 = *(const float4*)&sGt[blkL][ch][col0 * 12];
                const float4 ga1 = *(const float4*)&sGt[blkL][ch][col0 * 12 + 4];
                const float4 gb0 = *(const float4*)&sGt[blkL][ch][(col0 + 1) * 12];
                const float4 gb1 = *(const float4*)&sGt[blkL][ch][(col0 + 1) * 12 + 4];
                float p0 = 0.0f, p1 = 0.0f;
                p0 += cx0.x * ga0.x; p0 += cx0.y * ga0.y;
                p0 += cx0.z * ga0.z; p0 += cx0.w * ga0.w;
                p0 += cx1.x * ga1.x; p0 += cx1.y * ga1.y;
                p0 += cx1.z * ga1.z; p0 += cx1.w * ga1.w;
                p1 += cx0.x * gb0.x; p1 += cx0.y * gb0.y;
                p1 += cx0.z * gb0.z; p1 += cx0.w * gb0.w;
                p1 += cx1.x * gb1.x; p1 += cx1.y * gb1.y;
                p1 += cx1.z * gb1.z; p1 += cx1.w * gb1.w;
                r0[ch] = p0 * 0.25f;
                r1[ch] = p1 * 0.25f;
            }
        }
        {
            const float yvA = r0[0] + 128.0f, cbA = r0[1], crA = r0[2];
            const float yvB = r1[0] + 128.0f, cbB = r1[1], crB = r1[2];
            const float roA = yvA + 1.402f * crA;
            const float goA = yvA - 0.344136f * cbA - 0.714136f * crA;
            const float boA = yvA + 1.772f * cbA;
            const float roB = yvB + 1.402f * crB;
            const float goB = yvB - 0.344136f * cbB - 0.714136f * crB;
            const float boB = yvB + 1.772f * cbB;
            const size_t ob = rowbase + 2 * py;   // global cols: blkL*8+col0 == 2*py
            *(float2*)(out + ob) =
                make_float2(clamp255(roA), clamp255(roB));
            *(float2*)(out + ob + PLANE) =
                make_float2(clamp255(goA), clamp255(goB));
            *(float2*)(out + ob + 2 * (size_t)PLANE) =
                make_float2(clamp255(boA), clamp255(boB));
        }

        // rotate prefetched pixels into current
        Rc = Rn; Gc = Gn; Bc = Bn; rowbase = rbn;
    }
}

extern "C" void kernel_launch(void* const* d_in, const int* in_sizes, int n_in,
                              void* d_out, int out_size, void* d_ws, size_t ws_size,
                              hipStream_t stream) {
    const float* in = (const float*)d_in[0];
    float* out = (float*)d_out;
    jpeg_kernel<<<NWG, 64, 0, stream>>>(in, out);
}

// Round 9
// 147.552 us; speedup vs baseline: 1.3519x; 1.3519x over previous
//
#include <hip/hip_runtime.h>

namespace {

constexpr int BATCH = 16;
constexpr int HH = 512;
constexpr int WW = 512;
constexpr int PLANE = HH * WW;
constexpr int NPAIR = BATCH * (HH / 8) * (WW / 16);  // 32768 block-pairs
constexpr int NWG = 16384;                           // ITERS=2, fine tails

// ---- numpy-faithful cosine table (decision-path numerics) ----
constexpr double PI64 = 3.141592653589793;
constexpr double PI_LO = 1.2246467991473532e-16;
constexpr double PI_HI = (double)((long long)(PI64 * 17592186044416.0)) / 17592186044416.0;
constexpr double PI_MID = PI64 - PI_HI;

constexpr double CD9[9] = {
    1.0,
    0.9807852804032304491,
    0.9238795325112867561,
    0.8314696123025452371,
    0.7071067811865475244,
    0.5555702330196022248,
    0.3826834323650897717,
    0.1950903220161282678,
    0.0};
constexpr double cos_tab(int m) {
    m %= 32;
    double s = 1.0;
    if (m > 16) m = 32 - m;
    if (m > 8) { s = -1.0; m = 16 - m; }
    return s * CD9[m];
}
constexpr double sin_tab(int m) { return cos_tab(m + 24); }

constexpr double cx64(int K) {
    float Kf = (float)K;
    float p32 = (float)PI64;
    float t32 = Kf * p32;
    double F = (double)t32;
    double E = ((F - (double)K * PI_HI) - (double)K * PI_MID) - (double)K * PI_LO;
    double r = E / 16.0;
    double C = cos_tab(K), S = sin_tab(K);
    double cr = 1.0 - 0.5 * r * r;
    double sr = r - (r * r * r) / 6.0;
    return C * cr - S * sr;
}
constexpr float cx32(int x, int u) { return (float)cx64((2 * x + 1) * u); }

struct C32A { float c[64]; };
constexpr C32A make_c32f() {
    C32A a{};
    for (int x = 0; x < 8; ++x)
        for (int u = 0; u < 8; ++u)
            a.c[x * 8 + u] = cx32(x, u);
    return a;
}
constexpr C32A C32F = make_c32f();

constexpr float YQ[64] = {
    16, 11, 10, 16, 24, 40, 51, 61,
    12, 12, 14, 19, 26, 58, 60, 55,
    14, 13, 16, 24, 40, 57, 69, 56,
    14, 17, 22, 29, 51, 87, 80, 62,
    18, 22, 37, 56, 68, 109, 103, 77,
    24, 35, 55, 64, 81, 104, 113, 92,
    49, 64, 78, 87, 103, 121, 120, 101,
    72, 92, 95, 98, 112, 100, 103, 99};

constexpr float CQ[64] = {
    17, 18, 24, 47, 99, 99, 99, 99,
    18, 21, 26, 66, 99, 99, 99, 99,
    24, 26, 56, 99, 99, 99, 99, 99,
    47, 66, 99, 99, 99, 99, 99, 99,
    99, 99, 99, 99, 99, 99, 99, 99,
    99, 99, 99, 99, 99, 99, 99, 99,
    99, 99, 99, 99, 99, 99, 99, 99,
    99, 99, 99, 99, 99, 99, 99, 99};

constexpr float AL32 = (float)0.7071067811865475244;

} // namespace

// fp64 color transform — bit-identical (decision path).
__device__ __forceinline__ void color_f64(float Rf, float Gf, float Bf,
                                          double& yv, double& cbv, double& crv) {
    const double rv = ((double)Rf + 1.0) * 127.5;
    const double gv = ((double)Gf + 1.0) * 127.5;
    const double bv = ((double)Bf + 1.0) * 127.5;
    yv = ((double)0.299f * rv + (double)0.587f * gv) + (double)0.114f * bv;
    yv = yv - 128.0;
    cbv = ((double)-0.168736f * rv + (double)-0.331264f * gv) + (double)0.5f * bv;
    cbv = (cbv + 128.0) - 128.0;
    crv = ((double)0.5f * rv + (double)-0.418688f * gv) + (double)-0.081312f * bv;
    crv = (crv + 128.0) - 128.0;
}

__device__ __forceinline__ float clamp255(float x) {
    return fminf(fmaxf(x, 0.0f), 255.0f) * (1.0f / 255.0f);
}

// One wave = one PAIR of adjacent 8x8 blocks per iteration.
// Same structure as R8 (shuffle stage-B/F-gather, sYd/sGt aliasing, pixel
// prefetch) but at __launch_bounds__(64,4): R8's (64,6) capped allocation at
// 85 regs < the ~100-reg demand and spilled loop state to scratch
// (FETCH 186MB / WRITE 215MB). At 128-reg cap the RA fits everything;
// hardware occupancy follows ACTUAL allocation (<=102 regs -> 5 waves/SIMD).
__global__ __launch_bounds__(64, 4) void jpeg_kernel(const float* __restrict__ in,
                                                     float* __restrict__ out) {
    __shared__ __align__(16) char  sMem[3072];  // sYd, later aliased by sGt
    __shared__ __align__(16) float sC[64];      // fp32 cosines for IDCT

    double (*sYd)[3][64] = reinterpret_cast<double(*)[3][64]>(sMem);   // [blk][ch][x*8+y]
    float  (*sGt)[3][96] = reinterpret_cast<float(*)[3][96]>(sMem);    // [blk][ch][y*12+u]

    const int lane = threadIdx.x;     // 0..63
    const int px = lane >> 3;         // row within block / u-index
    const int py = lane & 7;          // col index        / v-index
    const int gbase = lane & 56;      // this lane's 8-lane group base (px*8)

    sC[lane] = C32F.c[lane];

    // per-lane f64 DCT factors (32 VGPRs, persistent):
    double cuD[8], cvD[8];
    #pragma unroll
    for (int k = 0; k < 8; ++k) {
        cuD[k] = (double)C32F.c[k * 8 + px];
        cvD[k] = (double)C32F.c[k * 8 + py];
    }

    // quant constants; f64 values re-derived per use exactly as the old QD table.
    const float yqf  = YQ[lane];
    const float cqf  = CQ[lane];
    const float aa32 = (px == 0 ? AL32 : 1.0f) * (py == 0 ? AL32 : 1.0f);
    const double aaD = (double)aa32;
    const double mQ  = (double)(aa32 * 0.25f);

    const int blkL = py >> 2;         // which block this lane's pixel-pair is in
    const int col0 = (py & 3) * 2;    // first of two adjacent columns in that block

    // ---- prologue: load first pair's pixels ----
    int P = blockIdx.x;
    size_t rowbase;
    float2 Rc, Gc, Bc;
    {
        const int b = P >> 11, p2 = P & 2047;
        rowbase = (size_t)b * 3 * PLANE + (size_t)((p2 >> 5) * 8 + px) * WW
                + (size_t)((p2 & 31) * 16);
        Rc = *(const float2*)(in + rowbase + 2 * py);
        Gc = *(const float2*)(in + rowbase + PLANE + 2 * py);
        Bc = *(const float2*)(in + rowbase + 2 * (size_t)PLANE + 2 * py);
    }

    #pragma unroll 1
    for (; P < NPAIR; P += NWG) {
        // ---- prefetch next pair (clamped; discarded on last iteration) ----
        const int Pn = (P + NWG < NPAIR) ? (P + NWG) : P;
        size_t rbn;
        {
            const int b = Pn >> 11, p2 = Pn & 2047;
            rbn = (size_t)b * 3 * PLANE + (size_t)((p2 >> 5) * 8 + px) * WW
                + (size_t)((p2 & 31) * 16);
        }
        const float2 Rn = *(const float2*)(in + rbn + 2 * py);
        const float2 Gn = *(const float2*)(in + rbn + PLANE + 2 * py);
        const float2 Bn = *(const float2*)(in + rbn + 2 * (size_t)PLANE + 2 * py);

        __syncthreads();   // Ba: prior iter's sGt reads done before sYd overwrite

        {
            double y0, cb0, cr0, y1, cb1, cr1;
            color_f64(Rc.x, Gc.x, Bc.x, y0, cb0, cr0);
            color_f64(Rc.y, Gc.y, Bc.y, y1, cb1, cr1);
            const int si = px * 8 + col0;
            *(double2*)&sYd[blkL][0][si] = make_double2(y0, y1);
            *(double2*)&sYd[blkL][1][si] = make_double2(cb0, cb1);
            *(double2*)&sYd[blkL][2][si] = make_double2(cr0, cr1);
        }
        __syncthreads();   // Bb: sYd complete

        // ---- DCT stage A: V[u=px][y=py] = sum_x cuD[x] * Y[x][py] (regs) ----
        double vA[3], vB[3];
        #pragma unroll
        for (int ch = 0; ch < 3; ++ch) {
            const double* __restrict__ Y0 = &sYd[0][ch][0];
            const double* __restrict__ Y1 = &sYd[1][ch][0];
            double a = 0.0, bb = 0.0;
            #pragma unroll
            for (int x = 0; x < 8; ++x) {
                a  = __builtin_fma(cuD[x], Y0[x * 8 + py], a);
                bb = __builtin_fma(cuD[x], Y1[x * 8 + py], bb);
            }
            vA[ch] = a; vB[ch] = bb;
        }

        // ---- DCT stage B via group shuffles + diff-round quant ----
        // V[px][y] lives at lane gbase+y; FMA order identical to R7 (y asc).
        float Fv0[3], Fv1[3];
        #pragma unroll
        for (int ch = 0; ch < 3; ++ch) {
            double sA = 0.0, sB = 0.0;
            #pragma unroll
            for (int y = 0; y < 8; ++y) {
                sA = __builtin_fma(cvD[y], __shfl(vA[ch], gbase + y, 64), sA);
                sB = __builtin_fma(cvD[y], __shfl(vB[ch], gbase + y, 64), sB);
            }
            const double qtd = (ch == 0) ? (double)yqf : (double)cqf;
            const double dq  = qtd * aaD;
            {
                const double f = (mQ * sA) / qtd;   // true f64 divide
                const double rr = __builtin_rint(f);
                const double d = f - rr;
                Fv0[ch] = (float)((rr + (d * d) * d) * dq);
            }
            {
                const double f = (mQ * sB) / qtd;
                const double rr = __builtin_rint(f);
                const double d = f - rr;
                Fv1[ch] = (float)((rr + (d * d) * d) * dq);
            }
        }

        __syncthreads();   // Bc: sYd reads done — sGt may overwrite (alias fence)

        // ---- idct1: G[u=px][y=py] = sum_v c[py][v]*F[px][v]; F via shuffles ----
        {
            const float4 cy0 = *(const float4*)&sC[py * 8];
            const float4 cy1 = *(const float4*)&sC[py * 8 + 4];
            #pragma unroll
            for (int ch = 0; ch < 3; ++ch) {
                float g0 = 0.0f, g1 = 0.0f;
                float f00 = __shfl(Fv0[ch], gbase + 0, 64);
                float f10 = __shfl(Fv1[ch], gbase + 0, 64);
                float f01 = __shfl(Fv0[ch], gbase + 1, 64);
                float f11 = __shfl(Fv1[ch], gbase + 1, 64);
                float f02 = __shfl(Fv0[ch], gbase + 2, 64);
                float f12 = __shfl(Fv1[ch], gbase + 2, 64);
                float f03 = __shfl(Fv0[ch], gbase + 3, 64);
                float f13 = __shfl(Fv1[ch], gbase + 3, 64);
                g0 += cy0.x * f00; g1 += cy0.x * f10;
                g0 += cy0.y * f01; g1 += cy0.y * f11;
                g0 += cy0.z * f02; g1 += cy0.z * f12;
                g0 += cy0.w * f03; g1 += cy0.w * f13;
                float f04 = __shfl(Fv0[ch], gbase + 4, 64);
                float f14 = __shfl(Fv1[ch], gbase + 4, 64);
                float f05 = __shfl(Fv0[ch], gbase + 5, 64);
                float f15 = __shfl(Fv1[ch], gbase + 5, 64);
                float f06 = __shfl(Fv0[ch], gbase + 6, 64);
                float f16 = __shfl(Fv1[ch], gbase + 6, 64);
                float f07 = __shfl(Fv0[ch], gbase + 7, 64);
                float f17 = __shfl(Fv1[ch], gbase + 7, 64);
                g0 += cy1.x * f04; g1 += cy1.x * f14;
                g0 += cy1.y * f05; g1 += cy1.y * f15;
                g0 += cy1.z * f06; g1 += cy1.z * f16;
                g0 += cy1.w * f07; g1 += cy1.w * f17;
                sGt[0][ch][py * 12 + px] = g0;   // (yy=py, uu=px)
                sGt[1][ch][py * 12 + px] = g1;
            }
        }
        __syncthreads();   // Bd: sGt complete

        // ---- idct2 + color-back: two ADJACENT pixels of blkL ----
        float r0[3], r1[3];
        {
            const float4 cx0 = *(const float4*)&sC[px * 8];
            const float4 cx1 = *(const float4*)&sC[px * 8 + 4];
            #pragma unroll
            for (int ch = 0; ch < 3; ++ch) {
                const float4 ga0 = *(const float4*)&sGt[blkL][ch][col0 * 12];
                const float4 ga1 = *(const float4*)&sGt[blkL][ch][col0 * 12 + 4];
                const float4 gb0 = *(const float4*)&sGt[blkL][ch][(col0 + 1) * 12];
                const float4 gb1 = *(const float4*)&sGt[blkL][ch][(col0 + 1) * 12 + 4];
                float p0 = 0.0f, p1 = 0.0f;
                p0 += cx0.x * ga0.x; p0 += cx0.y * ga0.y;
                p0 += cx0.z * ga0.z; p0 += cx0.w * ga0.w;
                p0 += cx1.x * ga1.x; p0 += cx1.y * ga1.y;
                p0 += cx1.z * ga1.z; p0 += cx1.w * ga1.w;
                p1 += cx0.x * gb0.x; p1 += cx0.y * gb0.y;
                p1 += cx0.z * gb0.z; p1 += cx0.w * gb0.w;
                p1 += cx1.x * gb1.x; p1 += cx1.y * gb1.y;
                p1 += cx1.z * gb1.z; p1 += cx1.w * gb1.w;
                r0[ch] = p0 * 0.25f;
                r1[ch] = p1 * 0.25f;
            }
        }
        {
            const float yvA = r0[0] + 128.0f, cbA = r0[1], crA = r0[2];
            const float yvB = r1[0] + 128.0f, cbB = r1[1], crB = r1[2];
            const float roA = yvA + 1.402f * crA;
            const float goA = yvA - 0.344136f * cbA - 0.714136f * crA;
            const float boA = yvA + 1.772f * cbA;
            const float roB = yvB + 1.402f * crB;
            const float goB = yvB - 0.344136f * cbB - 0.714136f * crB;
            const float boB = yvB + 1.772f * cbB;
            const size_t ob = rowbase + 2 * py;   // global cols: blkL*8+col0 == 2*py
            *(float2*)(out + ob) =
                make_float2(clamp255(roA), clamp255(roB));
            *(float2*)(out + ob + PLANE) =
                make_float2(clamp255(goA), clamp255(goB));
            *(float2*)(out + ob + 2 * (size_t)PLANE) =
                make_float2(clamp255(boA), clamp255(boB));
        }

        // rotate prefetched pixels into current
        Rc = Rn; Gc = Gn; Bc = Bn; rowbase = rbn;
    }
}

extern "C" void kernel_launch(void* const* d_in, const int* in_sizes, int n_in,
                              void* d_out, int out_size, void* d_ws, size_t ws_size,
                              hipStream_t stream) {
    const float* in = (const float*)d_in[0];
    float* out = (float*)d_out;
    jpeg_kernel<<<NWG, 64, 0, stream>>>(in, out);
}

// Round 10
// 141.094 us; speedup vs baseline: 1.4137x; 1.0458x over previous
//
#include <hip/hip_runtime.h>

namespace {

constexpr int BATCH = 16;
constexpr int HH = 512;
constexpr int WW = 512;
constexpr int PLANE = HH * WW;
constexpr int NPAIR = BATCH * (HH / 8) * (WW / 16);  // 32768 block-pairs
constexpr int NWG = 16384;                           // ITERS=2

// ---- numpy-faithful cosine table (decision-path numerics) ----
constexpr double PI64 = 3.141592653589793;
constexpr double PI_LO = 1.2246467991473532e-16;
constexpr double PI_HI = (double)((long long)(PI64 * 17592186044416.0)) / 17592186044416.0;
constexpr double PI_MID = PI64 - PI_HI;

constexpr double CD9[9] = {
    1.0,
    0.9807852804032304491,
    0.9238795325112867561,
    0.8314696123025452371,
    0.7071067811865475244,
    0.5555702330196022248,
    0.3826834323650897717,
    0.1950903220161282678,
    0.0};
constexpr double cos_tab(int m) {
    m %= 32;
    double s = 1.0;
    if (m > 16) m = 32 - m;
    if (m > 8) { s = -1.0; m = 16 - m; }
    return s * CD9[m];
}
constexpr double sin_tab(int m) { return cos_tab(m + 24); }

constexpr double cx64(int K) {
    float Kf = (float)K;
    float p32 = (float)PI64;
    float t32 = Kf * p32;
    double F = (double)t32;
    double E = ((F - (double)K * PI_HI) - (double)K * PI_MID) - (double)K * PI_LO;
    double r = E / 16.0;
    double C = cos_tab(K), S = sin_tab(K);
    double cr = 1.0 - 0.5 * r * r;
    double sr = r - (r * r * r) / 6.0;
    return C * cr - S * sr;
}
constexpr float cx32(int x, int u) { return (float)cx64((2 * x + 1) * u); }

struct C32A { float c[64]; };
constexpr C32A make_c32f() {
    C32A a{};
    for (int x = 0; x < 8; ++x)
        for (int u = 0; u < 8; ++u)
            a.c[x * 8 + u] = cx32(x, u);
    return a;
}
constexpr C32A C32F = make_c32f();

constexpr float YQ[64] = {
    16, 11, 10, 16, 24, 40, 51, 61,
    12, 12, 14, 19, 26, 58, 60, 55,
    14, 13, 16, 24, 40, 57, 69, 56,
    14, 17, 22, 29, 51, 87, 80, 62,
    18, 22, 37, 56, 68, 109, 103, 77,
    24, 35, 55, 64, 81, 104, 113, 92,
    49, 64, 78, 87, 103, 121, 120, 101,
    72, 92, 95, 98, 112, 100, 103, 99};

constexpr float CQ[64] = {
    17, 18, 24, 47, 99, 99, 99, 99,
    18, 21, 26, 66, 99, 99, 99, 99,
    24, 26, 56, 99, 99, 99, 99, 99,
    47, 66, 99, 99, 99, 99, 99, 99,
    99, 99, 99, 99, 99, 99, 99, 99,
    99, 99, 99, 99, 99, 99, 99, 99,
    99, 99, 99, 99, 99, 99, 99, 99,
    99, 99, 99, 99, 99, 99, 99, 99};

constexpr float AL32 = (float)0.7071067811865475244;

} // namespace

// fp64 color transform — bit-identical (decision path).
__device__ __forceinline__ void color_f64(float Rf, float Gf, float Bf,
                                          double& yv, double& cbv, double& crv) {
    const double rv = ((double)Rf + 1.0) * 127.5;
    const double gv = ((double)Gf + 1.0) * 127.5;
    const double bv = ((double)Bf + 1.0) * 127.5;
    yv = ((double)0.299f * rv + (double)0.587f * gv) + (double)0.114f * bv;
    yv = yv - 128.0;
    cbv = ((double)-0.168736f * rv + (double)-0.331264f * gv) + (double)0.5f * bv;
    cbv = (cbv + 128.0) - 128.0;
    crv = ((double)0.5f * rv + (double)-0.418688f * gv) + (double)-0.081312f * bv;
    crv = (crv + 128.0) - 128.0;
}

__device__ __forceinline__ float clamp255(float x) {
    return fminf(fmaxf(x, 0.0f), 255.0f) * (1.0f / 255.0f);
}

// One wave = one PAIR of adjacent 8x8 blocks per iteration.
// R7's LDS pipeline (proven 60us; R9 proved shuffles are slower for f64
// gathers: 2x ds_bpermute each, serial on the dot chain, unvectorizable)
// + R9's pixel prefetch + LDS aliasing:
//   region A [0,3840): sYd (3072) -> overwritten by sV (3840) -> by sGt (2304)
//   stage A computes its 6 dots into REGS, barrier, then writes sV in-place.
// LDS 8704 -> 5632 B: residency cap 18 -> 28 blocks/CU (LDS no longer caps).
__global__ __launch_bounds__(64, 5) void jpeg_kernel(const float* __restrict__ in,
                                                     float* __restrict__ out) {
    __shared__ __align__(16) char  sMem[5376];  // region A (3840) + sF (1536)
    __shared__ __align__(16) float sC[64];      // fp32 cosines for IDCT

    double (*sYd)[3][64] = reinterpret_cast<double(*)[3][64]>(sMem);   // [blk][ch][x*8+y]
    double (*sV)[3][80]  = reinterpret_cast<double(*)[3][80]>(sMem);   // [blk][ch][u*10+y]
    float  (*sGt)[3][96] = reinterpret_cast<float(*)[3][96]>(sMem);    // [blk][ch][y*12+u]
    float  (*sF)[3][64]  = reinterpret_cast<float(*)[3][64]>(sMem + 3840);

    const int lane = threadIdx.x;     // 0..63
    const int px = lane >> 3;         // row within block / u-index
    const int py = lane & 7;          // col index        / v-index

    sC[lane] = C32F.c[lane];

    // per-lane f64 DCT factors (32 VGPRs, persistent):
    double cuD[8], cvD[8];
    #pragma unroll
    for (int k = 0; k < 8; ++k) {
        cuD[k] = (double)C32F.c[k * 8 + px];
        cvD[k] = (double)C32F.c[k * 8 + py];
    }

    // quant constants; f64 values re-derived per use exactly as the old QD table.
    const float yqf  = YQ[lane];
    const float cqf  = CQ[lane];
    const float aa32 = (px == 0 ? AL32 : 1.0f) * (py == 0 ? AL32 : 1.0f);
    const double aaD = (double)aa32;
    const double mQ  = (double)(aa32 * 0.25f);

    const int blkL = py >> 2;         // which block this lane's pixel-pair is in
    const int col0 = (py & 3) * 2;    // first of two adjacent columns in that block

    // ---- prologue: load first pair's pixels ----
    int P = blockIdx.x;
    size_t rowbase;
    float2 Rc, Gc, Bc;
    {
        const int b = P >> 11, p2 = P & 2047;
        rowbase = (size_t)b * 3 * PLANE + (size_t)((p2 >> 5) * 8 + px) * WW
                + (size_t)((p2 & 31) * 16);
        Rc = *(const float2*)(in + rowbase + 2 * py);
        Gc = *(const float2*)(in + rowbase + PLANE + 2 * py);
        Bc = *(const float2*)(in + rowbase + 2 * (size_t)PLANE + 2 * py);
    }

    #pragma unroll 1
    for (; P < NPAIR; P += NWG) {
        // ---- prefetch next pair (clamped; discarded on last iteration) ----
        const int Pn = (P + NWG < NPAIR) ? (P + NWG) : P;
        size_t rbn;
        {
            const int b = Pn >> 11, p2 = Pn & 2047;
            rbn = (size_t)b * 3 * PLANE + (size_t)((p2 >> 5) * 8 + px) * WW
                + (size_t)((p2 & 31) * 16);
        }
        const float2 Rn = *(const float2*)(in + rbn + 2 * py);
        const float2 Gn = *(const float2*)(in + rbn + PLANE + 2 * py);
        const float2 Bn = *(const float2*)(in + rbn + 2 * (size_t)PLANE + 2 * py);

        __syncthreads();   // B1: prior iter's sGt (region A) reads done

        {
            double y0, cb0, cr0, y1, cb1, cr1;
            color_f64(Rc.x, Gc.x, Bc.x, y0, cb0, cr0);
            color_f64(Rc.y, Gc.y, Bc.y, y1, cb1, cr1);
            const int si = px * 8 + col0;
            *(double2*)&sYd[blkL][0][si] = make_double2(y0, y1);
            *(double2*)&sYd[blkL][1][si] = make_double2(cb0, cb1);
            *(double2*)&sYd[blkL][2][si] = make_double2(cr0, cr1);
        }
        __syncthreads();   // B2: sYd complete

        // ---- DCT stage A into REGISTERS: V[u=px][y=py] = sum_x cuD[x]*Y[x][py] ----
        double vA[3], vB[3];
        #pragma unroll
        for (int ch = 0; ch < 3; ++ch) {
            const double* __restrict__ Y0 = &sYd[0][ch][0];
            const double* __restrict__ Y1 = &sYd[1][ch][0];
            double a = 0.0, bb = 0.0;
            #pragma unroll
            for (int x = 0; x < 8; ++x) {
                a  = __builtin_fma(cuD[x], Y0[x * 8 + py], a);
                bb = __builtin_fma(cuD[x], Y1[x * 8 + py], bb);
            }
            vA[ch] = a; vB[ch] = bb;
        }
        __syncthreads();   // B3: ALL sYd reads done — sV may overwrite region A

        #pragma unroll
        for (int ch = 0; ch < 3; ++ch) {
            sV[0][ch][px * 10 + py] = vA[ch];
            sV[1][ch][px * 10 + py] = vB[ch];
        }
        __syncthreads();   // B4: sV complete

        // ---- DCT stage B (double2 row reads, y-ascending order) + quant ----
        float Fv0[3], Fv1[3];
        #pragma unroll
        for (int ch = 0; ch < 3; ++ch) {
            const double2* __restrict__ VA = (const double2*)&sV[0][ch][px * 10];
            const double2* __restrict__ VB = (const double2*)&sV[1][ch][px * 10];
            double sA = 0.0, sB = 0.0;
            #pragma unroll
            for (int y2 = 0; y2 < 4; ++y2) {
                const double2 dA = VA[y2];
                const double2 dB = VB[y2];
                sA = __builtin_fma(cvD[2 * y2],     dA.x, sA);
                sA = __builtin_fma(cvD[2 * y2 + 1], dA.y, sA);
                sB = __builtin_fma(cvD[2 * y2],     dB.x, sB);
                sB = __builtin_fma(cvD[2 * y2 + 1], dB.y, sB);
            }
            const double qtd = (ch == 0) ? (double)yqf : (double)cqf;
            const double dq  = qtd * aaD;
            {
                const double f = (mQ * sA) / qtd;   // true f64 divide
                const double rr = __builtin_rint(f);
                const double d = f - rr;
                Fv0[ch] = (float)((rr + (d * d) * d) * dq);
            }
            {
                const double f = (mQ * sB) / qtd;
                const double rr = __builtin_rint(f);
                const double d = f - rr;
                Fv1[ch] = (float)((rr + (d * d) * d) * dq);
            }
        }
        #pragma unroll
        for (int ch = 0; ch < 3; ++ch) {
            sF[0][ch][lane] = Fv0[ch];
            sF[1][ch][lane] = Fv1[ch];
        }
        __syncthreads();   // B5: sV reads done (region A free), sF visible

        // ---- idct1: G[u][y] = sum_v c[y][v]*F[u][v]; store transposed [y][u] ----
        {
            const float4 cy0 = *(const float4*)&sC[py * 8];
            const float4 cy1 = *(const float4*)&sC[py * 8 + 4];
            #pragma unroll
            for (int blk = 0; blk < 2; ++blk)
                #pragma unroll
                for (int ch = 0; ch < 3; ++ch) {
                    const float4 f0 = *(const float4*)&sF[blk][ch][px * 8];
                    const float4 f1 = *(const float4*)&sF[blk][ch][px * 8 + 4];
                    float g = 0.0f;
                    g += cy0.x * f0.x; g += cy0.y * f0.y;
                    g += cy0.z * f0.z; g += cy0.w * f0.w;
                    g += cy1.x * f1.x; g += cy1.y * f1.y;
                    g += cy1.z * f1.z; g += cy1.w * f1.w;
                    sGt[blk][ch][py * 12 + px] = g;   // (yy=py, uu=px)
                }
        }
        __syncthreads();   // B6: sGt complete

        // ---- idct2 + color-back: two ADJACENT pixels of blkL ----
        float r0[3], r1[3];
        {
            const float4 cx0 = *(const float4*)&sC[px * 8];
            const float4 cx1 = *(const float4*)&sC[px * 8 + 4];
            #pragma unroll
            for (int ch = 0; ch < 3; ++ch) {
                const float4 ga0 = *(const float4*)&sGt[blkL][ch][col0 * 12];
                const float4 ga1 = *(const float4*)&sGt[blkL][ch][col0 * 12 + 4];
                const float4 gb0 = *(const float4*)&sGt[blkL][ch][(col0 + 1) * 12];
                const float4 gb1 = *(const float4*)&sGt[blkL][ch][(col0 + 1) * 12 + 4];
                float p0 = 0.0f, p1 = 0.0f;
                p0 += cx0.x * ga0.x; p0 += cx0.y * ga0.y;
                p0 += cx0.z * ga0.z; p0 += cx0.w * ga0.w;
                p0 += cx1.x * ga1.x; p0 += cx1.y * ga1.y;
                p0 += cx1.z * ga1.z; p0 += cx1.w * ga1.w;
                p1 += cx0.x * gb0.x; p1 += cx0.y * gb0.y;
                p1 += cx0.z * gb0.z; p1 += cx0.w * gb0.w;
                p1 += cx1.x * gb1.x; p1 += cx1.y * gb1.y;
                p1 += cx1.z * gb1.z; p1 += cx1.w * gb1.w;
                r0[ch] = p0 * 0.25f;
                r1[ch] = p1 * 0.25f;
            }
        }
        {
            const float yvA = r0[0] + 128.0f, cbA = r0[1], crA = r0[2];
            const float yvB = r1[0] + 128.0f, cbB = r1[1], crB = r1[2];
            const float roA = yvA + 1.402f * crA;
            const float goA = yvA - 0.344136f * cbA - 0.714136f * crA;
            const float boA = yvA + 1.772f * cbA;
            const float roB = yvB + 1.402f * crB;
            const float goB = yvB - 0.344136f * cbB - 0.714136f * crB;
            const float boB = yvB + 1.772f * cbB;
            const size_t ob = rowbase + 2 * py;   // global cols: blkL*8+col0 == 2*py
            *(float2*)(out + ob) =
                make_float2(clamp255(roA), clamp255(roB));
            *(float2*)(out + ob + PLANE) =
                make_float2(clamp255(goA), clamp255(goB));
            *(float2*)(out + ob + 2 * (size_t)PLANE) =
                make_float2(clamp255(boA), clamp255(boB));
        }

        // rotate prefetched pixels into current
        Rc = Rn; Gc = Gn; Bc = Bn; rowbase = rbn;
    }
}

extern "C" void kernel_launch(void* const* d_in, const int* in_sizes, int n_in,
                              void* d_out, int out_size, void* d_ws, size_t ws_size,
                              hipStream_t stream) {
    const float* in = (const float*)d_in[0];
    float* out = (float*)d_out;
    jpeg_kernel<<<NWG, 64, 0, stream>>>(in, out);
}

// Round 11
// 120.887 us; speedup vs baseline: 1.6501x; 1.1672x over previous
//
#include <hip/hip_runtime.h>

namespace {

constexpr int BATCH = 16;
constexpr int HH = 512;
constexpr int WW = 512;
constexpr int PLANE = HH * WW;
constexpr int NPAIR = BATCH * (HH / 8) * (WW / 16);  // 32768 block-pairs
constexpr int NWG = 4096;                            // 256-thread blocks, 4 waves each
constexpr int NWGP = NWG * 4;                        // 16384 wave-streams, ITERS=2
constexpr int WAVE_LDS = 5504;                       // 5376 + 128 pad (bank stagger)

// ---- numpy-faithful cosine table (decision-path numerics) ----
constexpr double PI64 = 3.141592653589793;
constexpr double PI_LO = 1.2246467991473532e-16;
constexpr double PI_HI = (double)((long long)(PI64 * 17592186044416.0)) / 17592186044416.0;
constexpr double PI_MID = PI64 - PI_HI;

constexpr double CD9[9] = {
    1.0,
    0.9807852804032304491,
    0.9238795325112867561,
    0.8314696123025452371,
    0.7071067811865475244,
    0.5555702330196022248,
    0.3826834323650897717,
    0.1950903220161282678,
    0.0};
constexpr double cos_tab(int m) {
    m %= 32;
    double s = 1.0;
    if (m > 16) m = 32 - m;
    if (m > 8) { s = -1.0; m = 16 - m; }
    return s * CD9[m];
}
constexpr double sin_tab(int m) { return cos_tab(m + 24); }

constexpr double cx64(int K) {
    float Kf = (float)K;
    float p32 = (float)PI64;
    float t32 = Kf * p32;
    double F = (double)t32;
    double E = ((F - (double)K * PI_HI) - (double)K * PI_MID) - (double)K * PI_LO;
    double r = E / 16.0;
    double C = cos_tab(K), S = sin_tab(K);
    double cr = 1.0 - 0.5 * r * r;
    double sr = r - (r * r * r) / 6.0;
    return C * cr - S * sr;
}
constexpr float cx32(int x, int u) { return (float)cx64((2 * x + 1) * u); }

struct C32A { float c[64]; };
constexpr C32A make_c32f() {
    C32A a{};
    for (int x = 0; x < 8; ++x)
        for (int u = 0; u < 8; ++u)
            a.c[x * 8 + u] = cx32(x, u);
    return a;
}
constexpr C32A C32F = make_c32f();

constexpr float YQ[64] = {
    16, 11, 10, 16, 24, 40, 51, 61,
    12, 12, 14, 19, 26, 58, 60, 55,
    14, 13, 16, 24, 40, 57, 69, 56,
    14, 17, 22, 29, 51, 87, 80, 62,
    18, 22, 37, 56, 68, 109, 103, 77,
    24, 35, 55, 64, 81, 104, 113, 92,
    49, 64, 78, 87, 103, 121, 120, 101,
    72, 92, 95, 98, 112, 100, 103, 99};

constexpr float CQ[64] = {
    17, 18, 24, 47, 99, 99, 99, 99,
    18, 21, 26, 66, 99, 99, 99, 99,
    24, 26, 56, 99, 99, 99, 99, 99,
    47, 66, 99, 99, 99, 99, 99, 99,
    99, 99, 99, 99, 99, 99, 99, 99,
    99, 99, 99, 99, 99, 99, 99, 99,
    99, 99, 99, 99, 99, 99, 99, 99,
    99, 99, 99, 99, 99, 99, 99, 99};

constexpr float AL32 = (float)0.7071067811865475244;

} // namespace

// fp64 color transform — bit-identical (decision path).
__device__ __forceinline__ void color_f64(float Rf, float Gf, float Bf,
                                          double& yv, double& cbv, double& crv) {
    const double rv = ((double)Rf + 1.0) * 127.5;
    const double gv = ((double)Gf + 1.0) * 127.5;
    const double bv = ((double)Bf + 1.0) * 127.5;
    yv = ((double)0.299f * rv + (double)0.587f * gv) + (double)0.114f * bv;
    yv = yv - 128.0;
    cbv = ((double)-0.168736f * rv + (double)-0.331264f * gv) + (double)0.5f * bv;
    cbv = (cbv + 128.0) - 128.0;
    crv = ((double)0.5f * rv + (double)-0.418688f * gv) + (double)-0.081312f * bv;
    crv = (crv + 128.0) - 128.0;
}

__device__ __forceinline__ float clamp255(float x) {
    return fminf(fmaxf(x, 0.0f), 255.0f) * (1.0f / 255.0f);
}

// Intra-wave LDS fence: orders this wave's DS ops across the alias boundaries.
// Replaces __syncthreads() — all LDS dependencies are now within one wave
// (each wave owns a private LDS slice), so no inter-wave barrier is needed.
__device__ __forceinline__ void lds_fence() {
    asm volatile("s_waitcnt lgkmcnt(0)" ::: "memory");
}

// 4 waves per 256-thread workgroup; each wave processes its OWN pair stream in
// a PRIVATE LDS slice (the ~16 workgroup-slot/CU limit pinned 1-wave blocks at
// ~13 waves/CU across R7-R10; 4-wave blocks lift the ceiling to 28 waves/CU).
// Per-wave pipeline = R10's (R7-verified numerics + aliased regions + prefetch).
__global__ __launch_bounds__(256, 4) void jpeg_kernel(const float* __restrict__ in,
                                                      float* __restrict__ out) {
    __shared__ __align__(16) char  sMem[4 * WAVE_LDS];  // private per-wave slices
    __shared__ __align__(16) float sC[64];              // shared read-only cosines

    const int tid  = threadIdx.x;
    const int wid  = tid >> 6;        // wave id 0..3
    const int lane = tid & 63;
    char* my = sMem + wid * WAVE_LDS;

    // region map within the wave's slice (lifetimes disjoint, fence-ordered):
    //   [0,3840):    sYd (3072) -> sV (3840) -> sGt (2304)   (aliased)
    //   [3840,5376): sF (1536)
    double (*sYd)[3][64] = reinterpret_cast<double(*)[3][64]>(my);
    double (*sV)[3][80]  = reinterpret_cast<double(*)[3][80]>(my);
    float  (*sGt)[3][96] = reinterpret_cast<float(*)[3][96]>(my);
    float  (*sF)[3][64]  = reinterpret_cast<float(*)[3][64]>(my + 3840);

    const int px = lane >> 3;         // row within block / u-index
    const int py = lane & 7;          // col index        / v-index

    sC[lane] = C32F.c[lane];          // every wave writes identical values

    // per-lane f64 DCT factors (32 VGPRs, persistent):
    double cuD[8], cvD[8];
    #pragma unroll
    for (int k = 0; k < 8; ++k) {
        cuD[k] = (double)C32F.c[k * 8 + px];
        cvD[k] = (double)C32F.c[k * 8 + py];
    }

    // quant constants; f64 values re-derived per use exactly as the old QD table.
    const float yqf  = YQ[lane];
    const float cqf  = CQ[lane];
    const float aa32 = (px == 0 ? AL32 : 1.0f) * (py == 0 ? AL32 : 1.0f);
    const double aaD = (double)aa32;
    const double mQ  = (double)(aa32 * 0.25f);

    const int blkL = py >> 2;         // which block this lane's pixel-pair is in
    const int col0 = (py & 3) * 2;    // first of two adjacent columns in that block

    // ---- prologue: load first pair's pixels ----
    int P = blockIdx.x * 4 + wid;     // 4 adjacent pairs per block (L2 locality)
    size_t rowbase;
    float2 Rc, Gc, Bc;
    {
        const int b = P >> 11, p2 = P & 2047;
        rowbase = (size_t)b * 3 * PLANE + (size_t)((p2 >> 5) * 8 + px) * WW
                + (size_t)((p2 & 31) * 16);
        Rc = *(const float2*)(in + rowbase + 2 * py);
        Gc = *(const float2*)(in + rowbase + PLANE + 2 * py);
        Bc = *(const float2*)(in + rowbase + 2 * (size_t)PLANE + 2 * py);
    }

    #pragma unroll 1
    for (; P < NPAIR; P += NWGP) {
        // ---- prefetch next pair (clamped; discarded on last iteration) ----
        const int Pn = (P + NWGP < NPAIR) ? (P + NWGP) : P;
        size_t rbn;
        {
            const int b = Pn >> 11, p2 = Pn & 2047;
            rbn = (size_t)b * 3 * PLANE + (size_t)((p2 >> 5) * 8 + px) * WW
                + (size_t)((p2 & 31) * 16);
        }
        const float2 Rn = *(const float2*)(in + rbn + 2 * py);
        const float2 Gn = *(const float2*)(in + rbn + PLANE + 2 * py);
        const float2 Bn = *(const float2*)(in + rbn + 2 * (size_t)PLANE + 2 * py);

        lds_fence();   // F1: this wave's prior-iter sGt reads done (alias WAR)

        {
            double y0, cb0, cr0, y1, cb1, cr1;
            color_f64(Rc.x, Gc.x, Bc.x, y0, cb0, cr0);
            color_f64(Rc.y, Gc.y, Bc.y, y1, cb1, cr1);
            const int si = px * 8 + col0;
            *(double2*)&sYd[blkL][0][si] = make_double2(y0, y1);
            *(double2*)&sYd[blkL][1][si] = make_double2(cb0, cb1);
            *(double2*)&sYd[blkL][2][si] = make_double2(cr0, cr1);
        }
        lds_fence();   // F2: sYd writes landed (intra-wave RAW through alias casts)

        // ---- DCT stage A into REGISTERS: V[u=px][y=py] = sum_x cuD[x]*Y[x][py] ----
        double vA[3], vB[3];
        #pragma unroll
        for (int ch = 0; ch < 3; ++ch) {
            const double* __restrict__ Y0 = &sYd[0][ch][0];
            const double* __restrict__ Y1 = &sYd[1][ch][0];
            double a = 0.0, bb = 0.0;
            #pragma unroll
            for (int x = 0; x < 8; ++x) {
                a  = __builtin_fma(cuD[x], Y0[x * 8 + py], a);
                bb = __builtin_fma(cuD[x], Y1[x * 8 + py], bb);
            }
            vA[ch] = a; vB[ch] = bb;
        }
        lds_fence();   // F3: sYd reads complete — sV may overwrite region A

        #pragma unroll
        for (int ch = 0; ch < 3; ++ch) {
            sV[0][ch][px * 10 + py] = vA[ch];
            sV[1][ch][px * 10 + py] = vB[ch];
        }
        lds_fence();   // F4: sV complete

        // ---- DCT stage B (double2 row reads, y-ascending order) + quant ----
        float Fv0[3], Fv1[3];
        #pragma unroll
        for (int ch = 0; ch < 3; ++ch) {
            const double2* __restrict__ VA = (const double2*)&sV[0][ch][px * 10];
            const double2* __restrict__ VB = (const double2*)&sV[1][ch][px * 10];
            double sA = 0.0, sB = 0.0;
            #pragma unroll
            for (int y2 = 0; y2 < 4; ++y2) {
                const double2 dA = VA[y2];
                const double2 dB = VB[y2];
                sA = __builtin_fma(cvD[2 * y2],     dA.x, sA);
                sA = __builtin_fma(cvD[2 * y2 + 1], dA.y, sA);
                sB = __builtin_fma(cvD[2 * y2],     dB.x, sB);
                sB = __builtin_fma(cvD[2 * y2 + 1], dB.y, sB);
            }
            const double qtd = (ch == 0) ? (double)yqf : (double)cqf;
            const double dq  = qtd * aaD;
            {
                const double f = (mQ * sA) / qtd;   // true f64 divide
                const double rr = __builtin_rint(f);
                const double d = f - rr;
                Fv0[ch] = (float)((rr + (d * d) * d) * dq);
            }
            {
                const double f = (mQ * sB) / qtd;
                const double rr = __builtin_rint(f);
                const double d = f - rr;
                Fv1[ch] = (float)((rr + (d * d) * d) * dq);
            }
        }
        #pragma unroll
        for (int ch = 0; ch < 3; ++ch) {
            sF[0][ch][lane] = Fv0[ch];
            sF[1][ch][lane] = Fv1[ch];
        }
        lds_fence();   // F5: sV reads done (region A free) + sF visible

        // ---- idct1: G[u][y] = sum_v c[y][v]*F[u][v]; store transposed [y][u] ----
        {
            const float4 cy0 = *(const float4*)&sC[py * 8];
            const float4 cy1 = *(const float4*)&sC[py * 8 + 4];
            #pragma unroll
            for (int blk = 0; blk < 2; ++blk)
                #pragma unroll
                for (int ch = 0; ch < 3; ++ch) {
                    const float4 f0 = *(const float4*)&sF[blk][ch][px * 8];
                    const float4 f1 = *(const float4*)&sF[blk][ch][px * 8 + 4];
                    float g = 0.0f;
                    g += cy0.x * f0.x; g += cy0.y * f0.y;
                    g += cy0.z * f0.z; g += cy0.w * f0.w;
                    g += cy1.x * f1.x; g += cy1.y * f1.y;
                    g += cy1.z * f1.z; g += cy1.w * f1.w;
                    sGt[blk][ch][py * 12 + px] = g;   // (yy=py, uu=px)
                }
        }
        lds_fence();   // F6: sGt complete

        // ---- idct2 + color-back: two ADJACENT pixels of blkL ----
        float r0[3], r1[3];
        {
            const float4 cx0 = *(const float4*)&sC[px * 8];
            const float4 cx1 = *(const float4*)&sC[px * 8 + 4];
            #pragma unroll
            for (int ch = 0; ch < 3; ++ch) {
                const float4 ga0 = *(const float4*)&sGt[blkL][ch][col0 * 12];
                const float4 ga1 = *(const float4*)&sGt[blkL][ch][col0 * 12 + 4];
                const float4 gb0 = *(const float4*)&sGt[blkL][ch][(col0 + 1) * 12];
                const float4 gb1 = *(const float4*)&sGt[blkL][ch][(col0 + 1) * 12 + 4];
                float p0 = 0.0f, p1 = 0.0f;
                p0 += cx0.x * ga0.x; p0 += cx0.y * ga0.y;
                p0 += cx0.z * ga0.z; p0 += cx0.w * ga0.w;
                p0 += cx1.x * ga1.x; p0 += cx1.y * ga1.y;
                p0 += cx1.z * ga1.z; p0 += cx1.w * ga1.w;
                p1 += cx0.x * gb0.x; p1 += cx0.y * gb0.y;
                p1 += cx0.z * gb0.z; p1 += cx0.w * gb0.w;
                p1 += cx1.x * gb1.x; p1 += cx1.y * gb1.y;
                p1 += cx1.z * gb1.z; p1 += cx1.w * gb1.w;
                r0[ch] = p0 * 0.25f;
                r1[ch] = p1 * 0.25f;
            }
        }
        {
            const float yvA = r0[0] + 128.0f, cbA = r0[1], crA = r0[2];
            const float yvB = r1[0] + 128.0f, cbB = r1[1], crB = r1[2];
            const float roA = yvA + 1.402f * crA;
            const float goA = yvA - 0.344136f * cbA - 0.714136f * crA;
            const float boA = yvA + 1.772f * cbA;
            const float roB = yvB + 1.402f * crB;
            const float goB = yvB - 0.344136f * cbB - 0.714136f * crB;
            const float boB = yvB + 1.772f * cbB;
            const size_t ob = rowbase + 2 * py;   // global cols: blkL*8+col0 == 2*py
            *(float2*)(out + ob) =
                make_float2(clamp255(roA), clamp255(roB));
            *(float2*)(out + ob + PLANE) =
                make_float2(clamp255(goA), clamp255(goB));
            *(float2*)(out + ob + 2 * (size_t)PLANE) =
                make_float2(clamp255(boA), clamp255(boB));
        }

        // rotate prefetched pixels into current
        Rc = Rn; Gc = Gn; Bc = Bn; rowbase = rbn;
    }
}

extern "C" void kernel_launch(void* const* d_in, const int* in_sizes, int n_in,
                              void* d_out, int out_size, void* d_ws, size_t ws_size,
                              hipStream_t stream) {
    const float* in = (const float*)d_in[0];
    float* out = (float*)d_out;
    jpeg_kernel<<<NWG, 256, 0, stream>>>(in, out);
}

// Round 12
// 120.413 us; speedup vs baseline: 1.6565x; 1.0039x over previous
//
#include <hip/hip_runtime.h>

namespace {

constexpr int BATCH = 16;
constexpr int HH = 512;
constexpr int WW = 512;
constexpr int PLANE = HH * WW;
constexpr int NPAIR = BATCH * (HH / 8) * (WW / 16);  // 32768 block-pairs
constexpr int NWG = 4096;                            // 256-thread blocks, 4 waves each
constexpr int NWGP = NWG * 4;                        // 16384 wave-streams, ITERS=2
constexpr int WAVE_LDS = 4608;                       // 3072 (A) + 1536 (sF)

// ---- numpy-faithful cosine table (decision-path numerics) ----
constexpr double PI64 = 3.141592653589793;
constexpr double PI_LO = 1.2246467991473532e-16;
constexpr double PI_HI = (double)((long long)(PI64 * 17592186044416.0)) / 17592186044416.0;
constexpr double PI_MID = PI64 - PI_HI;

constexpr double CD9[9] = {
    1.0,
    0.9807852804032304491,
    0.9238795325112867561,
    0.8314696123025452371,
    0.7071067811865475244,
    0.5555702330196022248,
    0.3826834323650897717,
    0.1950903220161282678,
    0.0};
constexpr double cos_tab(int m) {
    m %= 32;
    double s = 1.0;
    if (m > 16) m = 32 - m;
    if (m > 8) { s = -1.0; m = 16 - m; }
    return s * CD9[m];
}
constexpr double sin_tab(int m) { return cos_tab(m + 24); }

constexpr double cx64(int K) {
    float Kf = (float)K;
    float p32 = (float)PI64;
    float t32 = Kf * p32;
    double F = (double)t32;
    double E = ((F - (double)K * PI_HI) - (double)K * PI_MID) - (double)K * PI_LO;
    double r = E / 16.0;
    double C = cos_tab(K), S = sin_tab(K);
    double cr = 1.0 - 0.5 * r * r;
    double sr = r - (r * r * r) / 6.0;
    return C * cr - S * sr;
}
constexpr float cx32(int x, int u) { return (float)cx64((2 * x + 1) * u); }

struct C32A { float c[64]; };
constexpr C32A make_c32f() {
    C32A a{};
    for (int x = 0; x < 8; ++x)
        for (int u = 0; u < 8; ++u)
            a.c[x * 8 + u] = cx32(x, u);
    return a;
}
constexpr C32A C32F = make_c32f();

constexpr float YQ[64] = {
    16, 11, 10, 16, 24, 40, 51, 61,
    12, 12, 14, 19, 26, 58, 60, 55,
    14, 13, 16, 24, 40, 57, 69, 56,
    14, 17, 22, 29, 51, 87, 80, 62,
    18, 22, 37, 56, 68, 109, 103, 77,
    24, 35, 55, 64, 81, 104, 113, 92,
    49, 64, 78, 87, 103, 121, 120, 101,
    72, 92, 95, 98, 112, 100, 103, 99};

constexpr float CQ[64] = {
    17, 18, 24, 47, 99, 99, 99, 99,
    18, 21, 26, 66, 99, 99, 99, 99,
    24, 26, 56, 99, 99, 99, 99, 99,
    47, 66, 99, 99, 99, 99, 99, 99,
    99, 99, 99, 99, 99, 99, 99, 99,
    99, 99, 99, 99, 99, 99, 99, 99,
    99, 99, 99, 99, 99, 99, 99, 99,
    99, 99, 99, 99, 99, 99, 99, 99};

constexpr float AL32 = (float)0.7071067811865475244;

} // namespace

// fp64 color transform — bit-identical (decision path).
__device__ __forceinline__ void color_f64(float Rf, float Gf, float Bf,
                                          double& yv, double& cbv, double& crv) {
    const double rv = ((double)Rf + 1.0) * 127.5;
    const double gv = ((double)Gf + 1.0) * 127.5;
    const double bv = ((double)Bf + 1.0) * 127.5;
    yv = ((double)0.299f * rv + (double)0.587f * gv) + (double)0.114f * bv;
    yv = yv - 128.0;
    cbv = ((double)-0.168736f * rv + (double)-0.331264f * gv) + (double)0.5f * bv;
    cbv = (cbv + 128.0) - 128.0;
    crv = ((double)0.5f * rv + (double)-0.418688f * gv) + (double)-0.081312f * bv;
    crv = (crv + 128.0) - 128.0;
}

__device__ __forceinline__ float clamp255(float x) {
    return fminf(fmaxf(x, 0.0f), 255.0f) * (1.0f / 255.0f);
}

// Compiler-only ordering fence across LDS alias boundaries. All LDS hazards
// are intra-wave (private slices), and a wave's DS operations execute in
// program order through the LDS pipeline, so no hardware lgkmcnt drain is
// needed — the compiler auto-inserts counted lgkmcnt for its own ds_read
// value dependencies. (R11 used s_waitcnt lgkmcnt(0): 6 full drains/pair.)
__device__ __forceinline__ void cfence() {
    asm volatile("" ::: "memory");
}

// 4 waves per 256-thread workgroup; each wave processes its OWN pair stream
// in a PRIVATE 4608-B LDS slice. Per-wave pipeline = R7-verified numerics +
// aliased regions + pixel prefetch. sV stride 8 (stage-B reads are 8-lane
// broadcasts: address depends only on px, so the old stride-10 pad was dead).
__global__ __launch_bounds__(256, 4) void jpeg_kernel(const float* __restrict__ in,
                                                      float* __restrict__ out) {
    __shared__ __align__(16) char  sMem[4 * WAVE_LDS];  // private per-wave slices
    __shared__ __align__(16) float sC[64];              // cosines (startup only)

    const int tid  = threadIdx.x;
    const int wid  = tid >> 6;        // wave id 0..3
    const int lane = tid & 63;
    char* my = sMem + wid * WAVE_LDS;

    // region map within the wave's slice (lifetimes disjoint, fence-ordered):
    //   [0,3072):    sYd (3072) -> sV (3072, stride 8) -> sGt (2304)  (aliased)
    //   [3072,4608): sF (1536)
    double (*sYd)[3][64] = reinterpret_cast<double(*)[3][64]>(my);
    double (*sV)[3][64]  = reinterpret_cast<double(*)[3][64]>(my);
    float  (*sGt)[3][96] = reinterpret_cast<float(*)[3][96]>(my);
    float  (*sF)[3][64]  = reinterpret_cast<float(*)[3][64]>(my + 3072);

    const int px = lane >> 3;         // row within block / u-index
    const int py = lane & 7;          // col index        / v-index

    // ---- startup: cosines via LDS once, then hoisted to registers ----
    sC[lane] = C32F.c[lane];          // every wave writes identical values
    cfence();                         // same-wave write->read, DS in-order
    float cyv[8], cxu[8];             // idct rows, persistent (16 VGPRs)
    #pragma unroll
    for (int k = 0; k < 8; ++k) {
        cyv[k] = sC[py * 8 + k];
        cxu[k] = sC[px * 8 + k];
    }

    // per-lane f64 DCT factors (32 VGPRs, persistent):
    double cuD[8], cvD[8];
    #pragma unroll
    for (int k = 0; k < 8; ++k) {
        cuD[k] = (double)C32F.c[k * 8 + px];
        cvD[k] = (double)C32F.c[k * 8 + py];
    }

    // quant constants; f64 values re-derived per use exactly as the old QD table.
    const float yqf  = YQ[lane];
    const float cqf  = CQ[lane];
    const float aa32 = (px == 0 ? AL32 : 1.0f) * (py == 0 ? AL32 : 1.0f);
    const double aaD = (double)aa32;
    const double mQ  = (double)(aa32 * 0.25f);

    const int blkL = py >> 2;         // which block this lane's pixel-pair is in
    const int col0 = (py & 3) * 2;    // first of two adjacent columns in that block

    // ---- prologue: load first pair's pixels ----
    int P = blockIdx.x * 4 + wid;     // 4 adjacent pairs per block (L2 locality)
    size_t rowbase;
    float2 Rc, Gc, Bc;
    {
        const int b = P >> 11, p2 = P & 2047;
        rowbase = (size_t)b * 3 * PLANE + (size_t)((p2 >> 5) * 8 + px) * WW
                + (size_t)((p2 & 31) * 16);
        Rc = *(const float2*)(in + rowbase + 2 * py);
        Gc = *(const float2*)(in + rowbase + PLANE + 2 * py);
        Bc = *(const float2*)(in + rowbase + 2 * (size_t)PLANE + 2 * py);
    }

    #pragma unroll 1
    for (; P < NPAIR; P += NWGP) {
        // ---- prefetch next pair (clamped; discarded on last iteration) ----
        const int Pn = (P + NWGP < NPAIR) ? (P + NWGP) : P;
        size_t rbn;
        {
            const int b = Pn >> 11, p2 = Pn & 2047;
            rbn = (size_t)b * 3 * PLANE + (size_t)((p2 >> 5) * 8 + px) * WW
                + (size_t)((p2 & 31) * 16);
        }
        const float2 Rn = *(const float2*)(in + rbn + 2 * py);
        const float2 Gn = *(const float2*)(in + rbn + PLANE + 2 * py);
        const float2 Bn = *(const float2*)(in + rbn + 2 * (size_t)PLANE + 2 * py);

        cfence();   // F1: order prior-iter sGt reads before sYd overwrite (WAR)

        {
            double y0, cb0, cr0, y1, cb1, cr1;
            color_f64(Rc.x, Gc.x, Bc.x, y0, cb0, cr0);
            color_f64(Rc.y, Gc.y, Bc.y, y1, cb1, cr1);
            const int si = px * 8 + col0;
            *(double2*)&sYd[blkL][0][si] = make_double2(y0, y1);
            *(double2*)&sYd[blkL][1][si] = make_double2(cb0, cb1);
            *(double2*)&sYd[blkL][2][si] = make_double2(cr0, cr1);
        }
        cfence();   // F2: sYd writes before stage-A reads (RAW, DS in-order)

        // ---- DCT stage A into REGISTERS: V[u=px][y=py] = sum_x cuD[x]*Y[x][py] ----
        double vA[3], vB[3];
        #pragma unroll
        for (int ch = 0; ch < 3; ++ch) {
            const double* __restrict__ Y0 = &sYd[0][ch][0];
            const double* __restrict__ Y1 = &sYd[1][ch][0];
            double a = 0.0, bb = 0.0;
            #pragma unroll
            for (int x = 0; x < 8; ++x) {
                a  = __builtin_fma(cuD[x], Y0[x * 8 + py], a);
                bb = __builtin_fma(cuD[x], Y1[x * 8 + py], bb);
            }
            vA[ch] = a; vB[ch] = bb;
        }
        cfence();   // F3: sYd reads before sV overwrite (WAR)

        #pragma unroll
        for (int ch = 0; ch < 3; ++ch) {
            sV[0][ch][px * 8 + py] = vA[ch];
            sV[1][ch][px * 8 + py] = vB[ch];
        }
        cfence();   // F4: sV writes before stage-B reads (RAW)

        // ---- DCT stage B (double2 broadcast row reads, y-ascending) + quant ----
        float Fv0[3], Fv1[3];
        #pragma unroll
        for (int ch = 0; ch < 3; ++ch) {
            const double2* __restrict__ VA = (const double2*)&sV[0][ch][px * 8];
            const double2* __restrict__ VB = (const double2*)&sV[1][ch][px * 8];
            double sA = 0.0, sB = 0.0;
            #pragma unroll
            for (int y2 = 0; y2 < 4; ++y2) {
                const double2 dA = VA[y2];
                const double2 dB = VB[y2];
                sA = __builtin_fma(cvD[2 * y2],     dA.x, sA);
                sA = __builtin_fma(cvD[2 * y2 + 1], dA.y, sA);
                sB = __builtin_fma(cvD[2 * y2],     dB.x, sB);
                sB = __builtin_fma(cvD[2 * y2 + 1], dB.y, sB);
            }
            const double qtd = (ch == 0) ? (double)yqf : (double)cqf;
            const double dq  = qtd * aaD;
            {
                const double f = (mQ * sA) / qtd;   // true f64 divide
                const double rr = __builtin_rint(f);
                const double d = f - rr;
                Fv0[ch] = (float)((rr + (d * d) * d) * dq);
            }
            {
                const double f = (mQ * sB) / qtd;
                const double rr = __builtin_rint(f);
                const double d = f - rr;
                Fv1[ch] = (float)((rr + (d * d) * d) * dq);
            }
        }
        #pragma unroll
        for (int ch = 0; ch < 3; ++ch) {
            sF[0][ch][lane] = Fv0[ch];
            sF[1][ch][lane] = Fv1[ch];
        }
        cfence();   // F5: sV reads before sGt overwrite (WAR); sF RAW

        // ---- idct1: G[u][y] = sum_v c[y][v]*F[u][v]; store transposed [y][u] ----
        #pragma unroll
        for (int blk = 0; blk < 2; ++blk)
            #pragma unroll
            for (int ch = 0; ch < 3; ++ch) {
                const float4 f0 = *(const float4*)&sF[blk][ch][px * 8];
                const float4 f1 = *(const float4*)&sF[blk][ch][px * 8 + 4];
                float g = 0.0f;
                g += cyv[0] * f0.x; g += cyv[1] * f0.y;
                g += cyv[2] * f0.z; g += cyv[3] * f0.w;
                g += cyv[4] * f1.x; g += cyv[5] * f1.y;
                g += cyv[6] * f1.z; g += cyv[7] * f1.w;
                sGt[blk][ch][py * 12 + px] = g;   // (yy=py, uu=px)
            }
        cfence();   // F6: sGt writes before idct2 reads (RAW)

        // ---- idct2 + color-back: two ADJACENT pixels of blkL ----
        float r0[3], r1[3];
        #pragma unroll
        for (int ch = 0; ch < 3; ++ch) {
            const float4 ga0 = *(const float4*)&sGt[blkL][ch][col0 * 12];
            const float4 ga1 = *(const float4*)&sGt[blkL][ch][col0 * 12 + 4];
            const float4 gb0 = *(const float4*)&sGt[blkL][ch][(col0 + 1) * 12];
            const float4 gb1 = *(const float4*)&sGt[blkL][ch][(col0 + 1) * 12 + 4];
            float p0 = 0.0f, p1 = 0.0f;
            p0 += cxu[0] * ga0.x; p0 += cxu[1] * ga0.y;
            p0 += cxu[2] * ga0.z; p0 += cxu[3] * ga0.w;
            p0 += cxu[4] * ga1.x; p0 += cxu[5] * ga1.y;
            p0 += cxu[6] * ga1.z; p0 += cxu[7] * ga1.w;
            p1 += cxu[0] * gb0.x; p1 += cxu[1] * gb0.y;
            p1 += cxu[2] * gb0.z; p1 += cxu[3] * gb0.w;
            p1 += cxu[4] * gb1.x; p1 += cxu[5] * gb1.y;
            p1 += cxu[6] * gb1.z; p1 += cxu[7] * gb1.w;
            r0[ch] = p0 * 0.25f;
            r1[ch] = p1 * 0.25f;
        }
        {
            const float yvA = r0[0] + 128.0f, cbA = r0[1], crA = r0[2];
            const float yvB = r1[0] + 128.0f, cbB = r1[1], crB = r1[2];
            const float roA = yvA + 1.402f * crA;
            const float goA = yvA - 0.344136f * cbA - 0.714136f * crA;
            const float boA = yvA + 1.772f * cbA;
            const float roB = yvB + 1.402f * crB;
            const float goB = yvB - 0.344136f * cbB - 0.714136f * crB;
            const float boB = yvB + 1.772f * cbB;
            const size_t ob = rowbase + 2 * py;   // global cols: blkL*8+col0 == 2*py
            *(float2*)(out + ob) =
                make_float2(clamp255(roA), clamp255(roB));
            *(float2*)(out + ob + PLANE) =
                make_float2(clamp255(goA), clamp255(goB));
            *(float2*)(out + ob + 2 * (size_t)PLANE) =
                make_float2(clamp255(boA), clamp255(boB));
        }

        // rotate prefetched pixels into current
        Rc = Rn; Gc = Gn; Bc = Bn; rowbase = rbn;
    }
}

extern "C" void kernel_launch(void* const* d_in, const int* in_sizes, int n_in,
                              void* d_out, int out_size, void* d_ws, size_t ws_size,
                              hipStream_t stream) {
    const float* in = (const float*)d_in[0];
    float* out = (float*)d_out;
    jpeg_kernel<<<NWG, 256, 0, stream>>>(in, out);
}